// Round 6
// baseline (113.833 us; speedup 1.0000x reference)
//
#include <hip/hip_runtime.h>

// LowBitMixIn: out[b,o,t] = sum_{d=1..7} mixer[o,(o-d)&1023] * x[b, perm[(o-d)&1023], t]
// B=16, F=1024, T=4096, float32. Memory-bound streaming.
//
// R6: exactly R3 (best: 99.6us — LDS coefs, rolling window, 1-deep prefetch)
// with ONE change: plain stores instead of nontemporal. Theory: nt stores
// complete only at HBM-acceptance, and gfx9's single in-order vmcnt queue
// forces every window-load wait to drain older stores -> wave progress was
// rate-limited by store completion. Plain stores complete in L2.

#define F_DIM 1024
#define T_DIM 4096
#define T4 (T_DIM / 4)   // 1024 float4 per row
#define OCH 32           // o-rows per wave
#define ROWS_PER_BLOCK 128

typedef float fvec4 __attribute__((ext_vector_type(4)));

__global__ __launch_bounds__(256, 4) void lowbit_mix_kernel(
    const float* __restrict__ x, const float* __restrict__ mixer,
    const int* __restrict__ perm, float* __restrict__ out)
{
    __shared__ float sCoef[ROWS_PER_BLOCK][8]; // [row_in_block][d-1], d=1..8 (d=8 slot unused zero)
    __shared__ int   sPerm[136];               // perm[(block_o0 - 8 + j) & 1023]

    const int tid  = threadIdx.x;
    const int lane = tid & 63;
    const int w    = tid >> 6;                        // wave 0..3
    const int t4   = blockIdx.x * 64 + lane;          // float4 index along t
    const int block_o0 = blockIdx.y * ROWS_PER_BLOCK;
    const int b    = blockIdx.z;

    // ---- stage coefs + perm into LDS (once per block; sources are L2-resident) ----
#pragma unroll
    for (int idx = tid; idx < ROWS_PER_BLOCK * 8; idx += 256) {
        const int r = idx >> 3;
        const int d = (idx & 7) + 1;                  // d=1..8; d=8 entry is a true zero in mixer
        const int o = block_o0 + r;
        sCoef[r][d - 1] = mixer[(size_t)o * F_DIM + ((o - d) & (F_DIM - 1))];
    }
    if (tid < 136) {
        sPerm[tid] = perm[(block_o0 - 8 + tid) & (F_DIM - 1)];
    }
    __syncthreads();

    const fvec4* __restrict__ xb =
        reinterpret_cast<const fvec4*>(x) + (size_t)b * F_DIM * T4;
    fvec4* __restrict__ ob =
        reinterpret_cast<fvec4*>(out) + (size_t)b * F_DIM * T4;

    const int wbase = w * OCH;                        // this wave's first row within block
    // Rolling window: win[k] holds x-row for input index i = o-7+k (k=0..6)
    fvec4 win[7];
#pragma unroll
    for (int k = 0; k < 7; ++k) {
        win[k] = xb[(size_t)sPerm[wbase + 1 + k] * T4 + t4];
    }

#pragma unroll
    for (int oi = 0; oi < OCH; ++oi) {
        const int r = wbase + oi;                     // row within block
        const int o = block_o0 + r;                   // global output row

        // issue next row load early (consumed only at the END of next iter's FMA chain)
        fvec4 nxt;
        if (oi != OCH - 1) {
            nxt = xb[(size_t)sPerm[r + 8] * T4 + t4];
        }

        fvec4 acc = (fvec4)(0.f);
        // oldest (d=7, win[0]) first ... newest (d=1, win[6]) last
#pragma unroll
        for (int d = 7; d >= 1; --d) {
            const float c = sCoef[r][d - 1];
            acc += c * win[7 - d];
        }
        ob[(size_t)o * T4 + t4] = acc;                // plain store: completes in L2

        if (oi != OCH - 1) {
#pragma unroll
            for (int k = 0; k < 6; ++k) win[k] = win[k + 1];
            win[6] = nxt;
        }
    }
}

extern "C" void kernel_launch(void* const* d_in, const int* in_sizes, int n_in,
                              void* d_out, int out_size, void* d_ws, size_t ws_size,
                              hipStream_t stream) {
    const float* x     = (const float*)d_in[0];   // (16, 1024, 4096) f32
    const float* mixer = (const float*)d_in[1];   // (1024, 1024) f32
    const int*   perm  = (const int*)d_in[2];     // (1024,) i32
    float*       out   = (float*)d_out;           // (16, 1024, 4096) f32

    dim3 grid(T_DIM / 256,                 // 16 t-chunks (256 floats each)
              F_DIM / ROWS_PER_BLOCK,      // 8 o-tiles (128 rows: 4 waves x 32)
              16);                         // batch
    dim3 block(256);
    lowbit_mix_kernel<<<grid, block, 0, stream>>>(x, mixer, perm, out);
}

// Round 7
// 92.393 us; speedup vs baseline: 1.2321x; 1.2321x over previous
//
#include <hip/hip_runtime.h>

// LowBitMixIn: out[b,o,t] = sum_{d=1..7} mixer[o,(o-d)&1023] * x[b, perm[(o-d)&1023], t]
// B=16, F=1024, T=4096, float32. Memory-bound streaming.
//
// R7: R3 structure (LDS coefs/perm, rolling 7-row window, 1-deep prefetch,
// nontemporal stores) with ONE change: each lane covers TWO float4s per row
// (t4 and t4+64), so every row read/write is a contiguous 2KB wave access
// (2x dwordx4 back-to-back) instead of 1KB. Theory: HBM granule /
// read-write turnaround efficiency limits us at 4.2 of ~6.5 TB/s.

#define F_DIM 1024
#define T_DIM 4096
#define T4 (T_DIM / 4)   // 1024 float4 per row
#define OCH 32           // o-rows per wave
#define ROWS_PER_BLOCK 128

typedef float fvec4 __attribute__((ext_vector_type(4)));

__global__ __launch_bounds__(256, 4) void lowbit_mix_kernel(
    const float* __restrict__ x, const float* __restrict__ mixer,
    const int* __restrict__ perm, float* __restrict__ out)
{
    __shared__ float sCoef[ROWS_PER_BLOCK][8]; // [row_in_block][d-1], d=1..8 (slot 8 unused zero)
    __shared__ int   sPerm[136];               // perm[(block_o0 - 8 + j) & 1023]

    const int tid  = threadIdx.x;
    const int lane = tid & 63;
    const int w    = tid >> 6;                        // wave 0..3
    const int t4   = blockIdx.x * 128 + lane;         // first float4 index (covers t4, t4+64)
    const int block_o0 = blockIdx.y * ROWS_PER_BLOCK;
    const int b    = blockIdx.z;

    // ---- stage coefs + perm into LDS (once per block) ----
#pragma unroll
    for (int idx = tid; idx < ROWS_PER_BLOCK * 8; idx += 256) {
        const int r = idx >> 3;
        const int d = (idx & 7) + 1;
        const int o = block_o0 + r;
        sCoef[r][d - 1] = mixer[(size_t)o * F_DIM + ((o - d) & (F_DIM - 1))];
    }
    if (tid < 136) {
        sPerm[tid] = perm[(block_o0 - 8 + tid) & (F_DIM - 1)];
    }
    __syncthreads();

    const fvec4* __restrict__ xb =
        reinterpret_cast<const fvec4*>(x) + (size_t)b * F_DIM * T4;
    fvec4* __restrict__ ob =
        reinterpret_cast<fvec4*>(out) + (size_t)b * F_DIM * T4;

    const int wbase = w * OCH;                        // wave's first row within block
    // Rolling window: win[k][h] = x[row i=o-7+k][t4 + 64h]
    fvec4 win[7][2];
#pragma unroll
    for (int k = 0; k < 7; ++k) {
        const size_t rowoff = (size_t)sPerm[wbase + 1 + k] * T4 + t4;
        win[k][0] = xb[rowoff];
        win[k][1] = xb[rowoff + 64];
    }

#pragma unroll
    for (int oi = 0; oi < OCH; ++oi) {
        const int r = wbase + oi;                     // row within block
        const int o = block_o0 + r;                   // global output row

        // prefetch next row (2KB contiguous), consumed at END of next iter's chain
        fvec4 nxt0, nxt1;
        if (oi != OCH - 1) {
            const size_t rowoff = (size_t)sPerm[r + 8] * T4 + t4;
            nxt0 = xb[rowoff];
            nxt1 = xb[rowoff + 64];
        }

        fvec4 acc0 = (fvec4)(0.f);
        fvec4 acc1 = (fvec4)(0.f);
        // oldest (d=7) first ... newest (d=1) last
#pragma unroll
        for (int d = 7; d >= 1; --d) {
            const float c = sCoef[r][d - 1];
            acc0 += c * win[7 - d][0];
            acc1 += c * win[7 - d][1];
        }
        const size_t ooff = (size_t)o * T4 + t4;
        __builtin_nontemporal_store(acc0, &ob[ooff]);
        __builtin_nontemporal_store(acc1, &ob[ooff + 64]);

        if (oi != OCH - 1) {
#pragma unroll
            for (int k = 0; k < 6; ++k) { win[k][0] = win[k + 1][0]; win[k][1] = win[k + 1][1]; }
            win[6][0] = nxt0;
            win[6][1] = nxt1;
        }
    }
}

extern "C" void kernel_launch(void* const* d_in, const int* in_sizes, int n_in,
                              void* d_out, int out_size, void* d_ws, size_t ws_size,
                              hipStream_t stream) {
    const float* x     = (const float*)d_in[0];   // (16, 1024, 4096) f32
    const float* mixer = (const float*)d_in[1];   // (1024, 1024) f32
    const int*   perm  = (const int*)d_in[2];     // (1024,) i32
    float*       out   = (float*)d_out;           // (16, 1024, 4096) f32

    dim3 grid(T_DIM / 512,                 // 8 t-chunks (512 floats = 2KB each)
              F_DIM / ROWS_PER_BLOCK,      // 8 o-tiles (128 rows: 4 waves x 32)
              16);                         // batch
    dim3 block(256);
    lowbit_mix_kernel<<<grid, block, 0, stream>>>(x, mixer, perm, out);
}